// Round 9
// baseline (400.229 us; speedup 1.0000x reference)
//
#include <hip/hip_runtime.h>

#define N_    8192
#define FIN_  256
#define NHID_ 128
#define E_    524288
#define KTOP  32
#define CAP   160    // bucket capacity per row; Binomial(E,1/N): mean 64, sigma 8 -> 160 = +12 sigma
#define HASHSZ 512   // LDS hash slots (kept entries <= CAP -> load factor <= 31%)

typedef unsigned short ushort_t;
typedef float v4f __attribute__((ext_vector_type(4)));   // native vector: NT-store-able

// ---- fused: edge scatter + h = relu(x @ W1 + b1) + a,b epilogue ----
__global__ __launch_bounds__(256) void k_fused(const float* __restrict__ x,
                                               const int* __restrict__ ei,
                                               const float* __restrict__ W1,
                                               const float* __restrict__ b1,
                                               const float* __restrict__ We,
                                               float* __restrict__ h,
                                               float* __restrict__ a,
                                               float* __restrict__ b,
                                               int* __restrict__ cnt,
                                               ushort_t* __restrict__ ecol) {
    __shared__ float xs[16][FIN_];
    int t = threadIdx.x;
    int blk = blockIdx.x;

    // ---- scatter slice: 1024 edges, int4-coalesced (cnt pre-zeroed by memset) ----
    {
        int4 r4 = ((const int4*)ei)[blk * 256 + t];
        int4 c4 = ((const int4*)(ei + E_))[blk * 256 + t];
        int p;
        p = atomicAdd(&cnt[r4.x], 1); if (p < CAP) ecol[r4.x * CAP + p] = (ushort_t)c4.x;
        p = atomicAdd(&cnt[r4.y], 1); if (p < CAP) ecol[r4.y * CAP + p] = (ushort_t)c4.y;
        p = atomicAdd(&cnt[r4.z], 1); if (p < CAP) ecol[r4.z * CAP + p] = (ushort_t)c4.z;
        p = atomicAdd(&cnt[r4.w], 1); if (p < CAP) ecol[r4.w * CAP + p] = (ushort_t)c4.w;
    }

    // ---- stage 16 rows of x into LDS: 1024 float4, 4 per thread ----
    int row0 = blk * 16;
    const float4* xg = (const float4*)(x + (size_t)row0 * FIN_);
    float4* xs4 = (float4*)&xs[0][0];
#pragma unroll
    for (int i = 0; i < 4; ++i) xs4[t + 256 * i] = xg[t + 256 * i];
    __syncthreads();

    int rg = t >> 5;           // row-group: rows 2*rg, 2*rg+1
    int jg = t & 31;           // col-group: cols 4*jg .. 4*jg+3
    int r0 = 2 * rg, r1 = 2 * rg + 1;
    const float* wp = W1 + jg * 4;
    float4 bb = *(const float4*)(b1 + jg * 4);
    float4 acc0 = bb, acc1 = bb;
    const float* xr0 = xs[r0];
    const float* xr1 = xs[r1];
#pragma unroll 8
    for (int k = 0; k < FIN_; ++k) {
        float4 w = *(const float4*)(wp + (size_t)k * NHID_);
        float x0 = xr0[k], x1 = xr1[k];
        acc0.x = fmaf(x0, w.x, acc0.x);
        acc0.y = fmaf(x0, w.y, acc0.y);
        acc0.z = fmaf(x0, w.z, acc0.z);
        acc0.w = fmaf(x0, w.w, acc0.w);
        acc1.x = fmaf(x1, w.x, acc1.x);
        acc1.y = fmaf(x1, w.y, acc1.y);
        acc1.z = fmaf(x1, w.z, acc1.z);
        acc1.w = fmaf(x1, w.w, acc1.w);
    }
    acc0.x = fmaxf(acc0.x, 0.f); acc0.y = fmaxf(acc0.y, 0.f);
    acc0.z = fmaxf(acc0.z, 0.f); acc0.w = fmaxf(acc0.w, 0.f);
    acc1.x = fmaxf(acc1.x, 0.f); acc1.y = fmaxf(acc1.y, 0.f);
    acc1.z = fmaxf(acc1.z, 0.f); acc1.w = fmaxf(acc1.w, 0.f);
    *(float4*)(h + (size_t)(row0 + r0) * NHID_ + jg * 4) = acc0;
    *(float4*)(h + (size_t)(row0 + r1) * NHID_ + jg * 4) = acc1;

    // ---- epilogue: a,b per-node scalars (32-lane tree per row) ----
    float4 we1 = *(const float4*)(We + jg * 4);
    float4 we2 = *(const float4*)(We + NHID_ + jg * 4);
    float p0 = acc0.x * we1.x + acc0.y * we1.y + acc0.z * we1.z + acc0.w * we1.w;
    float q0 = acc0.x * we2.x + acc0.y * we2.y + acc0.z * we2.z + acc0.w * we2.w;
    float p1 = acc1.x * we1.x + acc1.y * we1.y + acc1.z * we1.z + acc1.w * we1.w;
    float q1 = acc1.x * we2.x + acc1.y * we2.y + acc1.z * we2.z + acc1.w * we2.w;
#pragma unroll
    for (int o = 16; o > 0; o >>= 1) {
        p0 += __shfl_down(p0, o, 32);
        q0 += __shfl_down(q0, o, 32);
        p1 += __shfl_down(p1, o, 32);
        q1 += __shfl_down(q1, o, 32);
    }
    if (jg == 0) {
        a[row0 + r0] = p0; b[row0 + r0] = q0;
        a[row0 + r1] = p1; b[row0 + r1] = q1;
    }
}

// ---- per-row sparsemax + unique-topK -> compact kept list (one wave per row) ----
__global__ __launch_bounds__(64) void k_compute(const int* __restrict__ cnt,
                                                const ushort_t* __restrict__ ecol,
                                                const float* __restrict__ a,
                                                const float* __restrict__ b,
                                                const float* __restrict__ be,
                                                int* __restrict__ kcnt,
                                                ushort_t* __restrict__ kcol,
                                                float* __restrict__ kval) {
    __shared__ float zs[CAP];
    __shared__ int   cols[CAP];
    __shared__ float srt[CAP];
    __shared__ unsigned char dupf[CAP];
    __shared__ float s_tau, s_thresh;
    __shared__ int   s_kc;

    int r = blockIdx.x;
    int t = threadIdx.x;   // 0..63, single wave
    int m = cnt[r];
    if (m > CAP) m = CAP;
    if (m == 0) { if (t == 0) kcnt[r] = 0; return; }

    if (t == 0) { s_kc = 0; s_thresh = 0.f; }
    float ab = a[r] + be[0];
    for (int i = t; i < m; i += 64) {
        int c = (int)ecol[r * CAP + i];
        cols[i] = c;
        zs[i] = ab + b[c];
    }
    __syncthreads();

    // phase 1: descending rank (ties by bucket index) + duplicate-col flags
    for (int i = t; i < m; i += 64) {
        float zi = zs[i];
        int ci = cols[i];
        int rank = 0;
        for (int jj = 0; jj < m; ++jj) {
            float zj = zs[jj];
            rank += (zj > zi) || (zj == zi && jj < i);
        }
        bool dup = false;
        for (int jj = 0; jj < i; ++jj)
            if (cols[jj] == ci) { dup = true; break; }
        srt[rank] = zi;
        dupf[i] = dup ? 1 : 0;
    }
    __syncthreads();

    // phase 2: sparsemax support size + tau (serial on lane 0; m <= 160)
    if (t == 0) {
        float c = 0.f;
        int kmax = 1;
        float csk = srt[0];
        for (int jj = 0; jj < m; ++jj) {
            c += srt[jj];
            if (1.0f + (float)(jj + 1) * srt[jj] > c) { kmax = jj + 1; csk = c; }
        }
        s_tau = (csk - 1.0f) / (float)kmax;
    }
    __syncthreads();
    float tau = s_tau;

    // phase 3: K-th largest among UNIQUE cols (dups collapse in dense adj)
    for (int i = t; i < m; i += 64) {
        if (dupf[i]) continue;
        float zi = zs[i];
        int rank = 0;
        for (int jj = 0; jj < m; ++jj) {
            if (dupf[jj] || jj == i) continue;
            float zj = zs[jj];
            rank += (zj > zi) || (zj == zi && jj < i);
        }
        if (rank == KTOP - 1) {       // at most one element (strict total order)
            float s = zi - tau;
            s_thresh = s > 0.f ? s : 0.f;
        }
    }
    __syncthreads();
    float thresh = s_thresh;

    // phase 4: emit compact kept list (unique cols only)
    for (int i = t; i < m; i += 64) {
        if (dupf[i]) continue;
        float s = zs[i] - tau;
        if (s > 0.f && s >= thresh) {
            int slot = atomicAdd(&s_kc, 1);
            kcol[r * CAP + slot] = (ushort_t)cols[i];
            kval[r * CAP + slot] = s;
        }
    }
    __syncthreads();
    if (t == 0) kcnt[r] = s_kc;
}

// ---- pure streaming writer: bitmap+hash from kept list, then NT v4f stream ----
__global__ __launch_bounds__(256) void k_write(const int* __restrict__ kcnt,
                                               const ushort_t* __restrict__ kcol,
                                               const float* __restrict__ kval,
                                               float* __restrict__ adj) {
    __shared__ unsigned int bitmap[N_ / 32];   // 256 words, 1 KB
    __shared__ int   hcol[HASHSZ];             // 2 KB
    __shared__ float hval[HASHSZ];             // 2 KB

    int r = blockIdx.x;
    int t = threadIdx.x;
    int kc = kcnt[r];

    bitmap[t] = 0u;
    hcol[t] = -1;
    hcol[t + 256] = -1;
    __syncthreads();

    for (int i = t; i < kc; i += 256) {
        int c = (int)kcol[r * CAP + i];
        float s = kval[r * CAP + i];
        atomicOr(&bitmap[c >> 5], 1u << (c & 31));
        int slot = c & (HASHSZ - 1);
        while (atomicCAS(&hcol[slot], -1, c) != -1)
            slot = (slot + 1) & (HASHSZ - 1);
        hval[slot] = s;
    }
    __syncthreads();

    v4f* row4 = (v4f*)(adj + (size_t)r * N_);
#pragma unroll
    for (int k2 = 0; k2 < 8; ++k2) {
        int idx = t + 256 * k2;                 // v4f index; cols 4*idx..4*idx+3
        unsigned int word = bitmap[idx >> 3];
        unsigned int nib = (word >> ((idx & 7) * 4)) & 0xFu;
        v4f v = (v4f)(0.f);
        if (nib) {
            int cbase = idx * 4;
#pragma unroll
            for (int bbit = 0; bbit < 4; ++bbit) {
                if (nib & (1u << bbit)) {
                    int c = cbase + bbit;
                    int slot = c & (HASHSZ - 1);
                    while (hcol[slot] != c) slot = (slot + 1) & (HASHSZ - 1);
                    v[bbit] = hval[slot];
                }
            }
        }
        __builtin_nontemporal_store(v, &row4[idx]);
    }
}

extern "C" void kernel_launch(void* const* d_in, const int* in_sizes, int n_in,
                              void* d_out, int out_size, void* d_ws, size_t ws_size,
                              hipStream_t stream) {
    const float* x  = (const float*)d_in[0];
    const int*   ei = (const int*)d_in[1];
    const float* W1 = (const float*)d_in[2];
    const float* b1 = (const float*)d_in[3];
    const float* We = (const float*)d_in[4];
    const float* be = (const float*)d_in[5];

    float* h_out   = (float*)d_out;                 // (N, NHID)
    float* adj_out = h_out + (size_t)N_ * NHID_;    // (N, N)

    float*    a    = (float*)d_ws;                  // N f32
    float*    b    = a + N_;                        // N f32
    int*      cnt  = (int*)(b + N_);                // N i32
    int*      kcnt = cnt + N_;                      // N i32
    ushort_t* ecol = (ushort_t*)(kcnt + N_);        // N*CAP u16
    ushort_t* kcol = ecol + (size_t)N_ * CAP;       // N*CAP u16
    float*    kval = (float*)(kcol + (size_t)N_ * CAP); // N*CAP f32

    (void)hipMemsetAsync(cnt, 0, N_ * sizeof(int), stream);
    k_fused  <<<512, 256, 0, stream>>>(x, ei, W1, b1, We, h_out, a, b, cnt, ecol);
    k_compute<<<N_, 64, 0, stream>>>(cnt, ecol, a, b, be, kcnt, kcol, kval);
    k_write  <<<N_, 256, 0, stream>>>(kcnt, kcol, kval, adj_out);
}

// Round 10
// 395.915 us; speedup vs baseline: 1.0109x; 1.0109x over previous
//
#include <hip/hip_runtime.h>

#define N_    8192
#define FIN_  256
#define NHID_ 128
#define E_    524288
#define KTOP  32
#define CAP   160    // bucket capacity per row; Binomial(E,1/N): mean 64, sigma 8 -> 160 = +12 sigma
#define HASHSZ 512   // LDS hash slots (kept entries <= CAP -> load factor <= 31%)

typedef unsigned short ushort_t;

// ---- fused: edge scatter + h = relu(x @ W1 + b1) + a,b epilogue (R7, unchanged) ----
__global__ __launch_bounds__(256) void k_fused(const float* __restrict__ x,
                                               const int* __restrict__ ei,
                                               const float* __restrict__ W1,
                                               const float* __restrict__ b1,
                                               const float* __restrict__ We,
                                               float* __restrict__ h,
                                               float* __restrict__ a,
                                               float* __restrict__ b,
                                               int* __restrict__ cnt,
                                               ushort_t* __restrict__ ecol) {
    __shared__ float xs[16][FIN_];
    int t = threadIdx.x;
    int blk = blockIdx.x;

    {
        int4 r4 = ((const int4*)ei)[blk * 256 + t];
        int4 c4 = ((const int4*)(ei + E_))[blk * 256 + t];
        int p;
        p = atomicAdd(&cnt[r4.x], 1); if (p < CAP) ecol[r4.x * CAP + p] = (ushort_t)c4.x;
        p = atomicAdd(&cnt[r4.y], 1); if (p < CAP) ecol[r4.y * CAP + p] = (ushort_t)c4.y;
        p = atomicAdd(&cnt[r4.z], 1); if (p < CAP) ecol[r4.z * CAP + p] = (ushort_t)c4.z;
        p = atomicAdd(&cnt[r4.w], 1); if (p < CAP) ecol[r4.w * CAP + p] = (ushort_t)c4.w;
    }

    int row0 = blk * 16;
    const float4* xg = (const float4*)(x + (size_t)row0 * FIN_);
    float4* xs4 = (float4*)&xs[0][0];
#pragma unroll
    for (int i = 0; i < 4; ++i) xs4[t + 256 * i] = xg[t + 256 * i];
    __syncthreads();

    int rg = t >> 5;
    int jg = t & 31;
    int r0 = 2 * rg, r1 = 2 * rg + 1;
    const float* wp = W1 + jg * 4;
    float4 bb = *(const float4*)(b1 + jg * 4);
    float4 acc0 = bb, acc1 = bb;
    const float* xr0 = xs[r0];
    const float* xr1 = xs[r1];
#pragma unroll 8
    for (int k = 0; k < FIN_; ++k) {
        float4 w = *(const float4*)(wp + (size_t)k * NHID_);
        float x0 = xr0[k], x1 = xr1[k];
        acc0.x = fmaf(x0, w.x, acc0.x);
        acc0.y = fmaf(x0, w.y, acc0.y);
        acc0.z = fmaf(x0, w.z, acc0.z);
        acc0.w = fmaf(x0, w.w, acc0.w);
        acc1.x = fmaf(x1, w.x, acc1.x);
        acc1.y = fmaf(x1, w.y, acc1.y);
        acc1.z = fmaf(x1, w.z, acc1.z);
        acc1.w = fmaf(x1, w.w, acc1.w);
    }
    acc0.x = fmaxf(acc0.x, 0.f); acc0.y = fmaxf(acc0.y, 0.f);
    acc0.z = fmaxf(acc0.z, 0.f); acc0.w = fmaxf(acc0.w, 0.f);
    acc1.x = fmaxf(acc1.x, 0.f); acc1.y = fmaxf(acc1.y, 0.f);
    acc1.z = fmaxf(acc1.z, 0.f); acc1.w = fmaxf(acc1.w, 0.f);
    *(float4*)(h + (size_t)(row0 + r0) * NHID_ + jg * 4) = acc0;
    *(float4*)(h + (size_t)(row0 + r1) * NHID_ + jg * 4) = acc1;

    float4 we1 = *(const float4*)(We + jg * 4);
    float4 we2 = *(const float4*)(We + NHID_ + jg * 4);
    float p0 = acc0.x * we1.x + acc0.y * we1.y + acc0.z * we1.z + acc0.w * we1.w;
    float q0 = acc0.x * we2.x + acc0.y * we2.y + acc0.z * we2.z + acc0.w * we2.w;
    float p1 = acc1.x * we1.x + acc1.y * we1.y + acc1.z * we1.z + acc1.w * we1.w;
    float q1 = acc1.x * we2.x + acc1.y * we2.y + acc1.z * we2.z + acc1.w * we2.w;
#pragma unroll
    for (int o = 16; o > 0; o >>= 1) {
        p0 += __shfl_down(p0, o, 32);
        q0 += __shfl_down(q0, o, 32);
        p1 += __shfl_down(p1, o, 32);
        q1 += __shfl_down(q1, o, 32);
    }
    if (jg == 0) {
        a[row0 + r0] = p0; b[row0 + r0] = q0;
        a[row0 + r1] = p1; b[row0 + r1] = q1;
    }
}

// ---- per-row sparsemax + topK: wave-0 register/shuffle compute + single write pass ----
__global__ __launch_bounds__(256) void k_rows(const int* __restrict__ cnt,
                                              const ushort_t* __restrict__ ecol,
                                              const float* __restrict__ a,
                                              const float* __restrict__ b,
                                              const float* __restrict__ be,
                                              float* __restrict__ adj) {
    __shared__ float zs[CAP];
    __shared__ int   cols[CAP];
    __shared__ float srt[CAP];
    __shared__ unsigned int bitmap[N_ / 32];   // 1 KB
    __shared__ int   hcol[HASHSZ];             // 2 KB
    __shared__ float hval[HASHSZ];             // 2 KB

    int r = blockIdx.x;
    int t = threadIdx.x;
    int m = cnt[r];
    if (m > CAP) m = CAP;

    // init bitmap + hash; load bucket (all 256 threads)
    bitmap[t] = 0u;
    hcol[t] = -1;
    hcol[t + 256] = -1;
    float ab = a[r] + be[0];
    for (int i = t; i < m; i += 256) {
        int c = (int)ecol[r * CAP + i];
        cols[i] = c;
        zs[i] = ab + b[c];
    }
    __syncthreads();

    // ---- wave 0 computes everything in registers/shuffles ----
    if (t < 64 && m > 0) {
        int lane = t;
        // up to 3 elements per lane, slot-major: index = slot*64 + lane
        float z0 = (lane       < m) ? zs[lane]       : 0.f;
        float z1 = (lane + 64  < m) ? zs[lane + 64]  : 0.f;
        float z2 = (lane + 128 < m) ? zs[lane + 128] : 0.f;
        int   c0 = (lane       < m) ? cols[lane]       : -1;
        int   c1 = (lane + 64  < m) ? cols[lane + 64]  : -2;
        int   c2 = (lane + 128 < m) ? cols[lane + 128] : -3;

        // phase 1: rank (desc, tie by index) + dup flags via m shuffle-broadcasts
        int  r0 = 0, r1 = 0, r2 = 0;
        bool d0 = false, d1 = false, d2 = false;
        if (m <= 64) {
            for (int jj = 0; jj < m; ++jj) {
                float zj = __shfl(z0, jj);
                int   cj = __shfl(c0, jj);
                r0 += (zj > z0) || (zj == z0 && jj < lane);
                d0 = d0 || (cj == c0 && jj < lane);
            }
        } else {
            for (int jj = 0; jj < m; ++jj) {
                int slot = jj >> 6, lj = jj & 63;
                float zj; int cj;
                if (slot == 0)      { zj = __shfl(z0, lj); cj = __shfl(c0, lj); }
                else if (slot == 1) { zj = __shfl(z1, lj); cj = __shfl(c1, lj); }
                else                { zj = __shfl(z2, lj); cj = __shfl(c2, lj); }
                int i1 = lane + 64, i2 = lane + 128;
                r0 += (zj > z0) || (zj == z0 && jj < lane);
                d0 = d0 || (cj == c0 && jj < lane);
                r1 += (zj > z1) || (zj == z1 && jj < i1);
                d1 = d1 || (cj == c1 && jj < i1);
                r2 += (zj > z2) || (zj == z2 && jj < i2);
                d2 = d2 || (cj == c2 && jj < i2);
            }
        }
        // scatter into sorted order (wave-local LDS; DS pipe is in-order)
        if (lane       < m) srt[r0] = z0;
        if (lane + 64  < m) srt[r1] = z1;
        if (lane + 128 < m) srt[r2] = z2;

        // phase 2: shuffle prefix-scan over sorted values -> kmax, tau
        float v0 = (lane       < m) ? srt[lane]       : 0.f;
        float v1 = (lane + 64  < m) ? srt[lane + 64]  : 0.f;
        float v2 = (lane + 128 < m) ? srt[lane + 128] : 0.f;
        float sc0 = v0, sc1 = v1, sc2 = v2;
#pragma unroll
        for (int o = 1; o < 64; o <<= 1) {
            float u0 = __shfl_up(sc0, o);
            float u1 = __shfl_up(sc1, o);
            float u2 = __shfl_up(sc2, o);
            if (lane >= o) { sc0 += u0; sc1 += u1; sc2 += u2; }
        }
        float tot0 = __shfl(sc0, 63);
        sc1 += tot0;
        float tot1 = __shfl(sc1, 63);
        sc2 += tot1;
        bool k0 = (lane       < m) && (1.f + (float)(lane + 1)   * v0 > sc0);
        bool k1 = (lane + 64  < m) && (1.f + (float)(lane + 65)  * v1 > sc1);
        bool k2 = (lane + 128 < m) && (1.f + (float)(lane + 129) * v2 > sc2);
        unsigned long long b0 = __ballot(k0), b1 = __ballot(k1), b2 = __ballot(k2);
        int kmax;
        if (b2)      kmax = 128 + 63 - (int)__builtin_clzll(b2) + 1;
        else if (b1) kmax = 64  + 63 - (int)__builtin_clzll(b1) + 1;
        else         kmax =       63 - (int)__builtin_clzll(b0) + 1;  // b0!=0: j=0 always true
        int ki = kmax - 1, ks = ki >> 6, kl = ki & 63;
        float csk = (ks == 0) ? __shfl(sc0, kl) : (ks == 1) ? __shfl(sc1, kl) : __shfl(sc2, kl);
        float tau = (csk - 1.f) / (float)kmax;

        // phase 3: K-th largest among UNIQUE cols (dup-masks in ballots)
        unsigned long long dm0 = __ballot(d0), dm1 = __ballot(d1), dm2 = __ballot(d2);
        int u0 = 0, u1 = 0, u2 = 0;
        for (int jj = 0; jj < m; ++jj) {
            int slot = jj >> 6, lj = jj & 63;
            unsigned long long dm = (slot == 0) ? dm0 : (slot == 1) ? dm1 : dm2;
            if ((dm >> lj) & 1ull) continue;     // uniform skip of dups
            float zj;
            if (slot == 0)      zj = __shfl(z0, lj);
            else if (slot == 1) zj = __shfl(z1, lj);
            else                zj = __shfl(z2, lj);
            u0 += (zj > z0) || (zj == z0 && jj < lane);
            u1 += (zj > z1) || (zj == z1 && jj < lane + 64);
            u2 += (zj > z2) || (zj == z2 && jj < lane + 128);
        }
        float cand = 0.f;
        if (lane       < m && !d0 && u0 == KTOP - 1) cand = fmaxf(cand, fmaxf(z0 - tau, 0.f));
        if (lane + 64  < m && !d1 && u1 == KTOP - 1) cand = fmaxf(cand, fmaxf(z1 - tau, 0.f));
        if (lane + 128 < m && !d2 && u2 == KTOP - 1) cand = fmaxf(cand, fmaxf(z2 - tau, 0.f));
#pragma unroll
        for (int o = 32; o > 0; o >>= 1) cand = fmaxf(cand, __shfl_down(cand, o));
        float thresh = __shfl(cand, 0);

        // phase 4: insert kept entries into bitmap + hash (unique cols only)
        float s;
        if (lane < m && !d0) {
            s = z0 - tau;
            if (s > 0.f && s >= thresh) {
                atomicOr(&bitmap[c0 >> 5], 1u << (c0 & 31));
                int slot = c0 & (HASHSZ - 1);
                while (atomicCAS(&hcol[slot], -1, c0) != -1) slot = (slot + 1) & (HASHSZ - 1);
                hval[slot] = s;
            }
        }
        if (lane + 64 < m && !d1) {
            s = z1 - tau;
            if (s > 0.f && s >= thresh) {
                atomicOr(&bitmap[c1 >> 5], 1u << (c1 & 31));
                int slot = c1 & (HASHSZ - 1);
                while (atomicCAS(&hcol[slot], -1, c1) != -1) slot = (slot + 1) & (HASHSZ - 1);
                hval[slot] = s;
            }
        }
        if (lane + 128 < m && !d2) {
            s = z2 - tau;
            if (s > 0.f && s >= thresh) {
                atomicOr(&bitmap[c2 >> 5], 1u << (c2 & 31));
                int slot = c2 & (HASHSZ - 1);
                while (atomicCAS(&hcol[slot], -1, c2) != -1) slot = (slot + 1) & (HASHSZ - 1);
                hval[slot] = s;
            }
        }
    }
    __syncthreads();

    // streaming pass: write the full 32 KB row once (mostly zeros), regular stores
    float4* row4 = (float4*)(adj + (size_t)r * N_);
#pragma unroll
    for (int k2 = 0; k2 < 8; ++k2) {
        int idx = t + 256 * k2;
        unsigned int word = bitmap[idx >> 3];
        unsigned int nib = (word >> ((idx & 7) * 4)) & 0xFu;
        float4 v = make_float4(0.f, 0.f, 0.f, 0.f);
        if (nib) {
            int cbase = idx * 4;
#pragma unroll
            for (int bbit = 0; bbit < 4; ++bbit) {
                if (nib & (1u << bbit)) {
                    int c = cbase + bbit;
                    int slot = c & (HASHSZ - 1);
                    while (hcol[slot] != c) slot = (slot + 1) & (HASHSZ - 1);
                    float val = hval[slot];
                    if (bbit == 0) v.x = val;
                    else if (bbit == 1) v.y = val;
                    else if (bbit == 2) v.z = val;
                    else v.w = val;
                }
            }
        }
        row4[idx] = v;
    }
}

extern "C" void kernel_launch(void* const* d_in, const int* in_sizes, int n_in,
                              void* d_out, int out_size, void* d_ws, size_t ws_size,
                              hipStream_t stream) {
    const float* x  = (const float*)d_in[0];
    const int*   ei = (const int*)d_in[1];
    const float* W1 = (const float*)d_in[2];
    const float* b1 = (const float*)d_in[3];
    const float* We = (const float*)d_in[4];
    const float* be = (const float*)d_in[5];

    float* h_out   = (float*)d_out;                 // (N, NHID)
    float* adj_out = h_out + (size_t)N_ * NHID_;    // (N, N)

    float*    a    = (float*)d_ws;                  // N f32
    float*    b    = a + N_;                        // N f32
    int*      cnt  = (int*)(b + N_);                // N i32
    ushort_t* ecol = (ushort_t*)(cnt + N_);         // N*CAP u16

    (void)hipMemsetAsync(cnt, 0, N_ * sizeof(int), stream);
    k_fused<<<512, 256, 0, stream>>>(x, ei, W1, b1, We, h_out, a, b, cnt, ecol);
    k_rows <<<N_, 256, 0, stream>>>(cnt, ecol, a, b, be, adj_out);
}